// Round 1
// baseline (3427.002 us; speedup 1.0000x reference)
//
#include <hip/hip_runtime.h>
#include <stdint.h>

// Round 1: bf16-MFMA GRU decoder with algebraic output-feedback fusion.
//   Wsum = Whh + Wih_out @ Wo folded per gate (r,z); n-gate keeps i_n / h_n split;
//   o-projection is a 5th N-section of the per-step GEMM (lagged by one step).
// Structure: m97 recipe (128x64 tile x sections, BK=32, global_load_lds w16,
// ds_read_b128 frags, mfma_f32_16x16x32_bf16, 2 barriers/K-step).

typedef unsigned short u16;
typedef __attribute__((ext_vector_type(8))) short bf8v;   // 8 bf16 in 4 VGPR
typedef __attribute__((ext_vector_type(4))) float f4v;

constexpr int DECN = 2;
constexpr int BB = 4096;   // batch
constexpr int HH = 1024;   // hidden
constexpr int ZZ = 256;    // z dim
constexpr int OO = 128;    // out dim
constexpr int TT = 32;     // steps
constexpr int GG = 3 * HH;     // 3072
constexpr int WR = 4 * HH + OO; // 4224 rows of Wbig
constexpr int ILD = OO + ZZ;   // 384, Wih leading dim

__device__ __forceinline__ float bf2f(u16 u) {
  uint32_t x = ((uint32_t)u) << 16;
  return __builtin_bit_cast(float, x);
}
__device__ __forceinline__ u16 f2bf(float f) {
  uint32_t x = __builtin_bit_cast(uint32_t, f);
  x += 0x7fffu + ((x >> 16) & 1u);
  return (u16)(x >> 16);
}
__device__ __forceinline__ float sigf(float x) { return 1.f / (1.f + __expf(-x)); }
__device__ __forceinline__ float tanh_fast(float x) { return 2.f / (1.f + __expf(-2.f * x)) - 1.f; }

__device__ __forceinline__ void load16(const u16* g, u16* l) {
  __builtin_amdgcn_global_load_lds(
      (const __attribute__((address_space(1))) unsigned int*)g,
      (__attribute__((address_space(3))) unsigned int*)l, 16, 0, 0);
}

// BM=128, BN=64 per section, BK=32, 256 threads = 4 waves as 2(M)x2(N).
// C[m][n] = sum_k A[m][k] * B[brow[s]+n][k]  (both operands K-contiguous bf16)
template <int NSEC>
__device__ __forceinline__ void gemm_core(
    const u16* __restrict__ A, int lda,
    const u16* __restrict__ Bm, int ldb,
    const int (&brow)[NSEC], int m0, int K,
    u16* Als, u16* Bls, f4v (&acc)[NSEC][4][2]) {
  const int tid = threadIdx.x;
  const int lane = tid & 63;
  const int wid = tid >> 6;
  const int wm = wid >> 1, wn = wid & 1;
  const int srow = lane >> 2;          // staging row within 16-row chunk
  const int scol = (lane & 3) * 8;     // staging col (elements)
  const int l15 = lane & 15;
  const int khalf = (lane >> 4) * 8;   // k-chunk for fragments

  for (int k0 = 0; k0 < K; k0 += 32) {
    // stage A tile [128][32] (2 rounds of 64 rows across 4 waves)
    const u16* ga = A + (size_t)(m0 + wid * 16 + srow) * lda + k0 + scol;
    load16(ga, Als + (wid * 16) * 32);
    load16(ga + (size_t)64 * lda, Als + (64 + wid * 16) * 32);
    // stage B tiles [NSEC][64][32]
#pragma unroll
    for (int s = 0; s < NSEC; ++s) {
      const u16* gb = Bm + (size_t)(brow[s] + wid * 16 + srow) * ldb + k0 + scol;
      load16(gb, Bls + (s * 64 + wid * 16) * 32);
    }
    __syncthreads();
    bf8v af[4];
#pragma unroll
    for (int mf = 0; mf < 4; ++mf)
      af[mf] = *(const bf8v*)(Als + (wm * 64 + mf * 16 + l15) * 32 + khalf);
#pragma unroll
    for (int s = 0; s < NSEC; ++s) {
#pragma unroll
      for (int nf = 0; nf < 2; ++nf) {
        bf8v bv = *(const bf8v*)(Bls + (s * 64 + wn * 32 + nf * 16 + l15) * 32 + khalf);
#pragma unroll
        for (int mf = 0; mf < 4; ++mf)
          acc[s][mf][nf] = __builtin_amdgcn_mfma_f32_16x16x32_bf16(af[mf], bv, acc[s][mf][nf], 0, 0, 0);
      }
    }
    __syncthreads();
  }
}

// ---------------- prep kernels ----------------

__global__ __launch_bounds__(256) void pack_kernel(const float* __restrict__ src, int ld, int col0,
                                                   u16* __restrict__ dst, int rows, int cols) {
  int i = blockIdx.x * 256 + threadIdx.x;
  if (i < rows * cols) {
    int r = i / cols, c = i - r * cols;
    dst[i] = f2bf(src[(size_t)r * ld + col0 + c]);
  }
}

__global__ __launch_bounds__(256) void wot_kernel(const float* __restrict__ wo, u16* __restrict__ dst) {
  int i = blockIdx.x * 256 + threadIdx.x;
  if (i < HH * OO) {
    int k = i / OO, c = i - k * OO;
    dst[i] = f2bf(wo[(size_t)c * HH + k]);  // WoT[k][c] = Wo[c][k]
  }
}

__global__ __launch_bounds__(256) void vec_kernel(
    const float* __restrict__ wih0, const float* __restrict__ wih1,
    const float* __restrict__ bih0, const float* __restrict__ bih1,
    const float* __restrict__ bhh0, const float* __restrict__ bhh1,
    const float* __restrict__ bo0, const float* __restrict__ bo1,
    float* __restrict__ d1, float* __restrict__ v2) {
  int i = blockIdx.x * 256 + threadIdx.x;
  if (i >= DECN * GG) return;
  int dec = i / GG, j = i - dec * GG;
  const float* wih = dec ? wih1 : wih0;
  const float* bo = dec ? bo1 : bo0;
  const float* bih = dec ? bih1 : bih0;
  const float* bhh = dec ? bhh1 : bhh0;
  float bc = 0.f;
  for (int c = 0; c < OO; ++c) bc += wih[(size_t)j * ILD + c] * bo[c];
  d1[i] = wih[(size_t)j * ILD + (OO - 1)] - bc;            // SOS column minus bcomb
  v2[i] = bih[j] + (j < 2 * HH ? bhh[j] : 0.f) + bc;       // merged biases for gzc
}

// comb = Wih_out @ Wo -> Wbig2 rows [0,3072): +Whh for r,z sections, pure for i_n
__global__ __launch_bounds__(256, 2) void comb_kernel(
    const u16* __restrict__ wio, const u16* __restrict__ wot,
    const float* __restrict__ whh0, const float* __restrict__ whh1,
    u16* __restrict__ wb2) {
  __shared__ u16 Als[128 * 32];
  __shared__ u16 Bls[64 * 32];
  const int dec = blockIdx.z, m0 = blockIdx.x * 128, n0 = blockIdx.y * 64;
  const int lane = threadIdx.x & 63, wid = threadIdx.x >> 6;
  const int wm = wid >> 1, wn = wid & 1;
  const int rbase = m0 + wm * 64 + ((lane >> 4) << 2);
  const int clb = wn * 32 + (lane & 15);
  int brow[1] = {n0};
  f4v acc[1][4][2];
#pragma unroll
  for (int mf = 0; mf < 4; ++mf)
#pragma unroll
    for (int nf = 0; nf < 2; ++nf)
#pragma unroll
      for (int r = 0; r < 4; ++r) acc[0][mf][nf][r] = 0.f;
  gemm_core<1>(wio + (size_t)dec * GG * OO, OO, wot + (size_t)dec * HH * OO, OO, brow, m0, OO, Als, Bls, acc);
  const float* whh = dec ? whh1 : whh0;
  u16* W2 = wb2 + (size_t)dec * WR * HH;
#pragma unroll
  for (int mf = 0; mf < 4; ++mf)
#pragma unroll
    for (int nf = 0; nf < 2; ++nf) {
      const int k = n0 + clb + nf * 16;
#pragma unroll
      for (int r = 0; r < 4; ++r) {
        const int j = rbase + mf * 16 + r;
        float v = acc[0][mf][nf][r] + (j < 2 * HH ? whh[(size_t)j * HH + k] : 0.f);
        W2[(size_t)j * HH + k] = f2bf(v);
      }
    }
}

// gzc = z @ Wihz.T + merged biases (bf16 store), M=4096 N=3072 K=256
__global__ __launch_bounds__(256, 2) void gzc_kernel(
    const u16* __restrict__ zbf, const u16* __restrict__ wzb,
    const float* __restrict__ v2, u16* __restrict__ gzc) {
  __shared__ u16 Als[128 * 32];
  __shared__ u16 Bls[64 * 32];
  const int dec = blockIdx.z, m0 = blockIdx.x * 128, n0 = blockIdx.y * 64;
  const int lane = threadIdx.x & 63, wid = threadIdx.x >> 6;
  const int wm = wid >> 1, wn = wid & 1;
  const int rbase = m0 + wm * 64 + ((lane >> 4) << 2);
  const int clb = wn * 32 + (lane & 15);
  int brow[1] = {n0};
  f4v acc[1][4][2];
#pragma unroll
  for (int mf = 0; mf < 4; ++mf)
#pragma unroll
    for (int nf = 0; nf < 2; ++nf)
#pragma unroll
      for (int r = 0; r < 4; ++r) acc[0][mf][nf][r] = 0.f;
  gemm_core<1>(zbf + (size_t)dec * BB * ZZ, ZZ, wzb + (size_t)dec * GG * ZZ, ZZ, brow, m0, ZZ, Als, Bls, acc);
  const float* vv = v2 + dec * GG;
  u16* out = gzc + (size_t)dec * BB * GG;
#pragma unroll
  for (int mf = 0; mf < 4; ++mf)
#pragma unroll
    for (int nf = 0; nf < 2; ++nf) {
      const int col = n0 + clb + nf * 16;
#pragma unroll
      for (int r = 0; r < 4; ++r) {
        const int row = rbase + mf * 16 + r;
        out[(size_t)row * GG + col] = f2bf(acc[0][mf][nf][r] + vv[col]);
      }
    }
}

// h0 = tanh(z @ Wi.T + bi) -> f32 + bf16 (buf 0)
__global__ __launch_bounds__(256, 2) void h0_kernel(
    const u16* __restrict__ zbf, const u16* __restrict__ wib,
    const float* __restrict__ bi0, const float* __restrict__ bi1,
    float* __restrict__ hf, u16* __restrict__ hbf) {
  __shared__ u16 Als[128 * 32];
  __shared__ u16 Bls[64 * 32];
  const int dec = blockIdx.z, m0 = blockIdx.x * 128, n0 = blockIdx.y * 64;
  const int lane = threadIdx.x & 63, wid = threadIdx.x >> 6;
  const int wm = wid >> 1, wn = wid & 1;
  const int rbase = m0 + wm * 64 + ((lane >> 4) << 2);
  const int clb = wn * 32 + (lane & 15);
  int brow[1] = {n0};
  f4v acc[1][4][2];
#pragma unroll
  for (int mf = 0; mf < 4; ++mf)
#pragma unroll
    for (int nf = 0; nf < 2; ++nf)
#pragma unroll
      for (int r = 0; r < 4; ++r) acc[0][mf][nf][r] = 0.f;
  gemm_core<1>(zbf + (size_t)dec * BB * ZZ, ZZ, wib + (size_t)dec * HH * ZZ, ZZ, brow, m0, ZZ, Als, Bls, acc);
  const float* bi = dec ? bi1 : bi0;
  float* ho = hf + (size_t)dec * 2 * BB * HH;
  u16* hb = hbf + (size_t)dec * 2 * BB * HH;
#pragma unroll
  for (int mf = 0; mf < 4; ++mf)
#pragma unroll
    for (int nf = 0; nf < 2; ++nf) {
      const int col = n0 + clb + nf * 16;
#pragma unroll
      for (int r = 0; r < 4; ++r) {
        const int row = rbase + mf * 16 + r;
        float v = tanh_fast(acc[0][mf][nf][r] + bi[col]);
        ho[(size_t)row * HH + col] = v;
        hb[(size_t)row * HH + col] = f2bf(v);
      }
    }
}

// One GRU step. ntile<16: gate tile (4 sections r,z,i_n,h_n at hidden j0).
// ntile>=16: o-projection tile (section at rows 4096+c0), stores o_{t-1}.
__global__ __launch_bounds__(256, 2) void step_kernel(
    const u16* __restrict__ hbf_in, const float* __restrict__ hf_in,
    float* __restrict__ hf_out, u16* __restrict__ hbf_out,
    const u16* __restrict__ Wb, const u16* __restrict__ gzc,
    const float* __restrict__ d1,
    const float* __restrict__ bhh0v, const float* __restrict__ bhh1v,
    const float* __restrict__ bo0v, const float* __restrict__ bo1v,
    float* __restrict__ dout, int step1, int o_slot, int y_base) {
  __shared__ u16 Als[128 * 32];
  __shared__ u16 Bls[4 * 64 * 32];
  const int dec = blockIdx.z;
  const int ntile = blockIdx.y + y_base;
  const int m0 = blockIdx.x * 128;
  const int lane = threadIdx.x & 63, wid = threadIdx.x >> 6;
  const int wm = wid >> 1, wn = wid & 1;
  const int rbase = m0 + wm * 64 + ((lane >> 4) << 2);
  const int clb = wn * 32 + (lane & 15);
  const u16* A = hbf_in + (size_t)dec * 2 * BB * HH;
  const u16* W = Wb + (size_t)dec * WR * HH;

  if (ntile < 16) {
    const int j0 = ntile * 64;
    int brow[4] = {j0, HH + j0, 2 * HH + j0, 3 * HH + j0};
    const u16* gz = gzc + (size_t)dec * BB * GG;
    const float* dd = d1 + dec * GG;
    const float* bhhn = (dec ? bhh1v : bhh0v) + 2 * HH;
    f4v acc[4][4][2];
#pragma unroll
    for (int mf = 0; mf < 4; ++mf)
#pragma unroll
      for (int nf = 0; nf < 2; ++nf) {
        const int col = j0 + clb + nf * 16;
        const float dr0 = step1 ? dd[col] : 0.f;
        const float dr1 = step1 ? dd[HH + col] : 0.f;
        const float dr2 = step1 ? dd[2 * HH + col] : 0.f;
        const float bn = bhhn[col];
#pragma unroll
        for (int r = 0; r < 4; ++r) {
          const size_t ro = (size_t)(rbase + mf * 16 + r) * GG;
          acc[0][mf][nf][r] = bf2f(gz[ro + col]) + dr0;
          acc[1][mf][nf][r] = bf2f(gz[ro + HH + col]) + dr1;
          acc[2][mf][nf][r] = bf2f(gz[ro + 2 * HH + col]) + dr2;
          acc[3][mf][nf][r] = bn;
        }
      }
    gemm_core<4>(A, HH, W, HH, brow, m0, HH, Als, Bls, acc);
    const float* hold = hf_in + (size_t)dec * 2 * BB * HH;
    float* hnew = hf_out + (size_t)dec * 2 * BB * HH;
    u16* hnb = hbf_out + (size_t)dec * 2 * BB * HH;
#pragma unroll
    for (int mf = 0; mf < 4; ++mf)
#pragma unroll
      for (int nf = 0; nf < 2; ++nf) {
        const int col = j0 + clb + nf * 16;
#pragma unroll
        for (int r = 0; r < 4; ++r) {
          const int row = rbase + mf * 16 + r;
          float rg = sigf(acc[0][mf][nf][r]);
          float zg = sigf(acc[1][mf][nf][r]);
          float nn = tanh_fast(acc[2][mf][nf][r] + rg * acc[3][mf][nf][r]);
          float hv = hold[(size_t)row * HH + col];
          float hn = (1.f - zg) * nn + zg * hv;
          hnew[(size_t)row * HH + col] = hn;
          hnb[(size_t)row * HH + col] = f2bf(hn);
        }
      }
  } else {
    const int c0 = (ntile - 16) * 64;
    int brow[1] = {4 * HH + c0};
    const float* bod = dec ? bo1v : bo0v;
    f4v acc[1][4][2];
#pragma unroll
    for (int mf = 0; mf < 4; ++mf)
#pragma unroll
      for (int nf = 0; nf < 2; ++nf) {
        const float b = bod[c0 + clb + nf * 16];
#pragma unroll
        for (int r = 0; r < 4; ++r) acc[0][mf][nf][r] = b;
      }
    gemm_core<1>(A, HH, W, HH, brow, m0, HH, Als, Bls, acc);
    float* op = dout + (size_t)dec * BB * TT * OO + (size_t)o_slot * OO;
#pragma unroll
    for (int mf = 0; mf < 4; ++mf)
#pragma unroll
      for (int nf = 0; nf < 2; ++nf) {
        const int col = c0 + clb + nf * 16;
#pragma unroll
        for (int r = 0; r < 4; ++r) {
          const int row = rbase + mf * 16 + r;
          op[(size_t)row * TT * OO + col] = acc[0][mf][nf][r];
        }
      }
  }
}

// ---------------- host ----------------

extern "C" void kernel_launch(void* const* d_in, const int* in_sizes, int n_in,
                              void* d_out, int out_size, void* d_ws, size_t ws_size,
                              hipStream_t stream) {
  const float* z8[2] = {(const float*)d_in[0], (const float*)d_in[1]};
  const float* Wi[2] = {(const float*)d_in[4], (const float*)d_in[6]};
  const float* bi[2] = {(const float*)d_in[5], (const float*)d_in[7]};
  const float* Wih[2] = {(const float*)d_in[8], (const float*)d_in[12]};
  const float* Whh[2] = {(const float*)d_in[9], (const float*)d_in[13]};
  const float* bih[2] = {(const float*)d_in[10], (const float*)d_in[14]};
  const float* bhh[2] = {(const float*)d_in[11], (const float*)d_in[15]};
  const float* Wo[2] = {(const float*)d_in[16], (const float*)d_in[18]};
  const float* bo[2] = {(const float*)d_in[17], (const float*)d_in[19]};
  float* dout = (float*)d_out;

  char* p = (char*)d_ws;
  size_t off = 0;
  auto carve = [&](size_t nbytes) {
    char* r = p + off;
    off += (nbytes + 255) & ~(size_t)255;
    return (void*)r;
  };
  float* hf = (float*)carve((size_t)DECN * 2 * BB * HH * 4);   // [dec][buf][B][H]
  u16* hbf = (u16*)carve((size_t)DECN * 2 * BB * HH * 2);
  u16* gzc = (u16*)carve((size_t)DECN * BB * GG * 2);
  u16* wb1 = (u16*)carve((size_t)DECN * WR * HH * 2);
  u16* wb2 = (u16*)carve((size_t)DECN * WR * HH * 2);
  u16* zbf = (u16*)carve((size_t)DECN * BB * ZZ * 2);
  u16* wzb = (u16*)carve((size_t)DECN * GG * ZZ * 2);
  u16* wio = (u16*)carve((size_t)DECN * GG * OO * 2);
  u16* wib = (u16*)carve((size_t)DECN * HH * ZZ * 2);
  u16* wot = (u16*)carve((size_t)DECN * HH * OO * 2);
  float* d1v = (float*)carve((size_t)DECN * GG * 4);
  float* v2v = (float*)carve((size_t)DECN * GG * 4);
  (void)ws_size; (void)in_sizes; (void)n_in; (void)out_size;

  auto pack = [&](const float* src, int ld, int c0, u16* dst, int rows, int cols) {
    int n = rows * cols;
    pack_kernel<<<(n + 255) / 256, 256, 0, stream>>>(src, ld, c0, dst, rows, cols);
  };
  for (int d = 0; d < 2; ++d) {
    pack(z8[d], ZZ, 0, zbf + (size_t)d * BB * ZZ, BB, ZZ);
    pack(Wih[d], ILD, OO, wzb + (size_t)d * GG * ZZ, GG, ZZ);       // z-columns of Wih
    pack(Wih[d], ILD, 0, wio + (size_t)d * GG * OO, GG, OO);        // out-columns of Wih
    pack(Wi[d], ZZ, 0, wib + (size_t)d * HH * ZZ, HH, ZZ);
    pack(Whh[d], HH, 0, wb1 + (size_t)d * WR * HH, 2 * HH, HH);     // Wbig1 r,z = Whh
    pack(Whh[d] + (size_t)2 * HH * HH, HH, 0, wb1 + (size_t)d * WR * HH + (size_t)3 * HH * HH, HH, HH);
    pack(Whh[d] + (size_t)2 * HH * HH, HH, 0, wb2 + (size_t)d * WR * HH + (size_t)3 * HH * HH, HH, HH);
    pack(Wo[d], HH, 0, wb2 + (size_t)d * WR * HH + (size_t)4 * HH * HH, OO, HH);
    wot_kernel<<<(HH * OO + 255) / 256, 256, 0, stream>>>(Wo[d], wot + (size_t)d * HH * OO);
    hipMemsetAsync(wb1 + (size_t)d * WR * HH + (size_t)2 * HH * HH, 0, (size_t)HH * HH * 2, stream); // zero i_n section
  }
  vec_kernel<<<(DECN * GG + 255) / 256, 256, 0, stream>>>(
      Wih[0], Wih[1], bih[0], bih[1], bhh[0], bhh[1], bo[0], bo[1], d1v, v2v);
  comb_kernel<<<dim3(24, 16, 2), 256, 0, stream>>>(wio, wot, Whh[0], Whh[1], wb2);
  gzc_kernel<<<dim3(32, 48, 2), 256, 0, stream>>>(zbf, wzb, v2v, gzc);
  h0_kernel<<<dim3(32, 16, 2), 256, 0, stream>>>(zbf, wib, bi[0], bi[1], hf, hbf);

  for (int t = 1; t <= TT; ++t) {
    const int bin = (t - 1) & 1, bout = t & 1;
    dim3 grid(32, t == 1 ? 16 : 18, 2);
    step_kernel<<<grid, 256, 0, stream>>>(
        hbf + (size_t)bin * BB * HH, hf + (size_t)bin * BB * HH,
        hf + (size_t)bout * BB * HH, hbf + (size_t)bout * BB * HH,
        t == 1 ? wb1 : wb2, gzc, d1v, bhh[0], bhh[1], bo[0], bo[1],
        dout, t == 1 ? 1 : 0, t - 2, 0);
  }
  // final o_32 (h_32 lives in buf 0)
  step_kernel<<<dim3(32, 2, 2), 256, 0, stream>>>(
      hbf, hf, hf + (size_t)BB * HH, hbf + (size_t)BB * HH,
      wb2, gzc, d1v, bhh[0], bhh[1], bo[0], bo[1],
      dout, 0, TT - 1, 16);
}

// Round 5
// 3209.018 us; speedup vs baseline: 1.0679x; 1.0679x over previous
//
#include <hip/hip_runtime.h>
#include <stdint.h>

// Round 2 (resubmit x3): 8-phase counted-vmcnt step kernel (T2+T3+T4+T5), BM=256 BK=64,
// 8 waves, 128KB dbuf LDS, chunk^row&7 swizzle (pre-swizzled global source).
// Prep kernels unchanged from round 1.

typedef unsigned short u16;
typedef __attribute__((ext_vector_type(8))) short bf8v;   // 8 bf16 in 4 VGPR
typedef __attribute__((ext_vector_type(4))) float f4v;

constexpr int DECN = 2;
constexpr int BB = 4096;   // batch
constexpr int HH = 1024;   // hidden
constexpr int ZZ = 256;    // z dim
constexpr int OO = 128;    // out dim
constexpr int TT = 32;     // steps
constexpr int GG = 3 * HH;     // 3072
constexpr int WR = 4 * HH + OO; // 4224 rows of Wbig
constexpr int ILD = OO + ZZ;   // 384, Wih leading dim
constexpr int BK = 64;
constexpr int NKT = HH / BK;   // 16 K-tiles

__device__ __forceinline__ float bf2f(u16 u) {
  uint32_t x = ((uint32_t)u) << 16;
  return __builtin_bit_cast(float, x);
}
__device__ __forceinline__ u16 f2bf(float f) {
  uint32_t x = __builtin_bit_cast(uint32_t, f);
  x += 0x7fffu + ((x >> 16) & 1u);
  return (u16)(x >> 16);
}
__device__ __forceinline__ float sigf(float x) { return 1.f / (1.f + __expf(-x)); }
__device__ __forceinline__ float tanh_fast(float x) { return 2.f / (1.f + __expf(-2.f * x)) - 1.f; }

__device__ __forceinline__ void load16(const u16* g, u16* l) {
  __builtin_amdgcn_global_load_lds(
      (const __attribute__((address_space(1))) unsigned int*)g,
      (__attribute__((address_space(3))) unsigned int*)l, 16, 0, 0);
}

// ---------------- round-1 gemm core (prep kernels only) ----------------
template <int NSEC>
__device__ __forceinline__ void gemm_core(
    const u16* __restrict__ A, int lda,
    const u16* __restrict__ Bm, int ldb,
    const int (&brow)[NSEC], int m0, int K,
    u16* Als, u16* Bls, f4v (&acc)[NSEC][4][2]) {
  const int tid = threadIdx.x;
  const int lane = tid & 63;
  const int wid = tid >> 6;
  const int wm = wid >> 1, wn = wid & 1;
  const int srow = lane >> 2;
  const int scol = (lane & 3) * 8;
  const int l15 = lane & 15;
  const int khalf = (lane >> 4) * 8;

  for (int k0 = 0; k0 < K; k0 += 32) {
    const u16* ga = A + (size_t)(m0 + wid * 16 + srow) * lda + k0 + scol;
    load16(ga, Als + (wid * 16) * 32);
    load16(ga + (size_t)64 * lda, Als + (64 + wid * 16) * 32);
#pragma unroll
    for (int s = 0; s < NSEC; ++s) {
      const u16* gb = Bm + (size_t)(brow[s] + wid * 16 + srow) * ldb + k0 + scol;
      load16(gb, Bls + (s * 64 + wid * 16) * 32);
    }
    __syncthreads();
    bf8v af[4];
#pragma unroll
    for (int mf = 0; mf < 4; ++mf)
      af[mf] = *(const bf8v*)(Als + (wm * 64 + mf * 16 + l15) * 32 + khalf);
#pragma unroll
    for (int s = 0; s < NSEC; ++s) {
#pragma unroll
      for (int nf = 0; nf < 2; ++nf) {
        bf8v bv = *(const bf8v*)(Bls + (s * 64 + wn * 32 + nf * 16 + l15) * 32 + khalf);
#pragma unroll
        for (int mf = 0; mf < 4; ++mf)
          acc[s][mf][nf] = __builtin_amdgcn_mfma_f32_16x16x32_bf16(af[mf], bv, acc[s][mf][nf], 0, 0, 0);
      }
    }
    __syncthreads();
  }
}

// ---------------- prep kernels (unchanged) ----------------

__global__ __launch_bounds__(256) void pack_kernel(const float* __restrict__ src, int ld, int col0,
                                                   u16* __restrict__ dst, int rows, int cols) {
  int i = blockIdx.x * 256 + threadIdx.x;
  if (i < rows * cols) {
    int r = i / cols, c = i - r * cols;
    dst[i] = f2bf(src[(size_t)r * ld + col0 + c]);
  }
}

__global__ __launch_bounds__(256) void wot_kernel(const float* __restrict__ wo, u16* __restrict__ dst) {
  int i = blockIdx.x * 256 + threadIdx.x;
  if (i < HH * OO) {
    int k = i / OO, c = i - k * OO;
    dst[i] = f2bf(wo[(size_t)c * HH + k]);
  }
}

__global__ __launch_bounds__(256) void vec_kernel(
    const float* __restrict__ wih0, const float* __restrict__ wih1,
    const float* __restrict__ bih0, const float* __restrict__ bih1,
    const float* __restrict__ bhh0, const float* __restrict__ bhh1,
    const float* __restrict__ bo0, const float* __restrict__ bo1,
    float* __restrict__ d1, float* __restrict__ v2) {
  int i = blockIdx.x * 256 + threadIdx.x;
  if (i >= DECN * GG) return;
  int dec = i / GG, j = i - dec * GG;
  const float* wih = dec ? wih1 : wih0;
  const float* bo = dec ? bo1 : bo0;
  const float* bih = dec ? bih1 : bih0;
  const float* bhh = dec ? bhh1 : bhh0;
  float bc = 0.f;
  for (int c = 0; c < OO; ++c) bc += wih[(size_t)j * ILD + c] * bo[c];
  d1[i] = wih[(size_t)j * ILD + (OO - 1)] - bc;
  v2[i] = bih[j] + (j < 2 * HH ? bhh[j] : 0.f) + bc;
}

__global__ __launch_bounds__(256, 2) void comb_kernel(
    const u16* __restrict__ wio, const u16* __restrict__ wot,
    const float* __restrict__ whh0, const float* __restrict__ whh1,
    u16* __restrict__ wb2) {
  __shared__ u16 Als[128 * 32];
  __shared__ u16 Bls[64 * 32];
  const int dec = blockIdx.z, m0 = blockIdx.x * 128, n0 = blockIdx.y * 64;
  const int lane = threadIdx.x & 63, wid = threadIdx.x >> 6;
  const int wm = wid >> 1, wn = wid & 1;
  const int rbase = m0 + wm * 64 + ((lane >> 4) << 2);
  const int clb = wn * 32 + (lane & 15);
  int brow[1] = {n0};
  f4v acc[1][4][2];
#pragma unroll
  for (int mf = 0; mf < 4; ++mf)
#pragma unroll
    for (int nf = 0; nf < 2; ++nf)
#pragma unroll
      for (int r = 0; r < 4; ++r) acc[0][mf][nf][r] = 0.f;
  gemm_core<1>(wio + (size_t)dec * GG * OO, OO, wot + (size_t)dec * HH * OO, OO, brow, m0, OO, Als, Bls, acc);
  const float* whh = dec ? whh1 : whh0;
  u16* W2 = wb2 + (size_t)dec * WR * HH;
#pragma unroll
  for (int mf = 0; mf < 4; ++mf)
#pragma unroll
    for (int nf = 0; nf < 2; ++nf) {
      const int k = n0 + clb + nf * 16;
#pragma unroll
      for (int r = 0; r < 4; ++r) {
        const int j = rbase + mf * 16 + r;
        float v = acc[0][mf][nf][r] + (j < 2 * HH ? whh[(size_t)j * HH + k] : 0.f);
        W2[(size_t)j * HH + k] = f2bf(v);
      }
    }
}

__global__ __launch_bounds__(256, 2) void gzc_kernel(
    const u16* __restrict__ zbf, const u16* __restrict__ wzb,
    const float* __restrict__ v2, u16* __restrict__ gzc) {
  __shared__ u16 Als[128 * 32];
  __shared__ u16 Bls[64 * 32];
  const int dec = blockIdx.z, m0 = blockIdx.x * 128, n0 = blockIdx.y * 64;
  const int lane = threadIdx.x & 63, wid = threadIdx.x >> 6;
  const int wm = wid >> 1, wn = wid & 1;
  const int rbase = m0 + wm * 64 + ((lane >> 4) << 2);
  const int clb = wn * 32 + (lane & 15);
  int brow[1] = {n0};
  f4v acc[1][4][2];
#pragma unroll
  for (int mf = 0; mf < 4; ++mf)
#pragma unroll
    for (int nf = 0; nf < 2; ++nf)
#pragma unroll
      for (int r = 0; r < 4; ++r) acc[0][mf][nf][r] = 0.f;
  gemm_core<1>(zbf + (size_t)dec * BB * ZZ, ZZ, wzb + (size_t)dec * GG * ZZ, ZZ, brow, m0, ZZ, Als, Bls, acc);
  const float* vv = v2 + dec * GG;
  u16* out = gzc + (size_t)dec * BB * GG;
#pragma unroll
  for (int mf = 0; mf < 4; ++mf)
#pragma unroll
    for (int nf = 0; nf < 2; ++nf) {
      const int col = n0 + clb + nf * 16;
#pragma unroll
      for (int r = 0; r < 4; ++r) {
        const int row = rbase + mf * 16 + r;
        out[(size_t)row * GG + col] = f2bf(acc[0][mf][nf][r] + vv[col]);
      }
    }
}

__global__ __launch_bounds__(256, 2) void h0_kernel(
    const u16* __restrict__ zbf, const u16* __restrict__ wib,
    const float* __restrict__ bi0, const float* __restrict__ bi1,
    float* __restrict__ hf, u16* __restrict__ hbf) {
  __shared__ u16 Als[128 * 32];
  __shared__ u16 Bls[64 * 32];
  const int dec = blockIdx.z, m0 = blockIdx.x * 128, n0 = blockIdx.y * 64;
  const int lane = threadIdx.x & 63, wid = threadIdx.x >> 6;
  const int wm = wid >> 1, wn = wid & 1;
  const int rbase = m0 + wm * 64 + ((lane >> 4) << 2);
  const int clb = wn * 32 + (lane & 15);
  int brow[1] = {n0};
  f4v acc[1][4][2];
#pragma unroll
  for (int mf = 0; mf < 4; ++mf)
#pragma unroll
    for (int nf = 0; nf < 2; ++nf)
#pragma unroll
      for (int r = 0; r < 4; ++r) acc[0][mf][nf][r] = 0.f;
  gemm_core<1>(zbf + (size_t)dec * BB * ZZ, ZZ, wib + (size_t)dec * HH * ZZ, ZZ, brow, m0, ZZ, Als, Bls, acc);
  const float* bi = dec ? bi1 : bi0;
  float* ho = hf + (size_t)dec * 2 * BB * HH;
  u16* hb = hbf + (size_t)dec * 2 * BB * HH;
#pragma unroll
  for (int mf = 0; mf < 4; ++mf)
#pragma unroll
    for (int nf = 0; nf < 2; ++nf) {
      const int col = n0 + clb + nf * 16;
#pragma unroll
      for (int r = 0; r < 4; ++r) {
        const int row = rbase + mf * 16 + r;
        float v = tanh_fast(acc[0][mf][nf][r] + bi[col]);
        ho[(size_t)row * HH + col] = v;
        hb[(size_t)row * HH + col] = f2bf(v);
      }
    }
}

// ---------------- 8-phase step kernel ----------------
// LDS map (u16 elements): buf b: A at b*32768, B at b*32768+16384; row stride 64.
// Swizzle: 16B chunk c stored at c ^ (row&7); global source pre-swizzled.
template <int NS>
__device__ __forceinline__ void kloop8(
    const u16* __restrict__ A, const u16* __restrict__ W,
    const int (&brow)[4], int m0, u16* lds, int lane, int wid,
    f4v (&acc)[8][4]) {
  const int wm = wid >> 2, wn = wid & 3;
  const int l15 = lane & 15, lq = lane >> 4;
  const int srow = wid * 8 + (lane >> 3);           // staged row within 64-row round
  const int sgc = (lane & 7) ^ ((lane >> 3) & 7);   // pre-swizzled source chunk

  auto stA = [&](int kt, int r) {
    const u16* g = A + (size_t)(m0 + r * 64 + srow) * HH + kt * BK + sgc * 8;
    load16(g, lds + ((kt & 1) * 2) * 16384 + (r * 64 + wid * 8) * 64);
  };
  auto stB = [&](int kt, int r) {
    const u16* g = W + (size_t)(brow[r] + srow) * HH + kt * BK + sgc * 8;
    load16(g, lds + ((kt & 1) * 2 + 1) * 16384 + (r * 64 + wid * 8) * 64);
  };

  // prologue: stage tile 0, drain, barrier
  stB(0, 0); stB(0, 1); stB(0, 2); stB(0, 3);
  stA(0, 0); stA(0, 1); stA(0, 2); stA(0, 3);
  asm volatile("s_waitcnt vmcnt(0)" ::: "memory");
  __builtin_amdgcn_s_barrier();

  auto tile = [&](int kt, bool pf) {
    const u16* la = lds + (size_t)(kt & 1) * 32768;
    const u16* lb = la + 16384;
    bf8v bfr[NS][2];
#pragma unroll
    for (int q = 0; q < 4; ++q) {
      if (q == 0) {
#pragma unroll
        for (int s = 0; s < NS; ++s)
#pragma unroll
          for (int ks = 0; ks < 2; ++ks)
            bfr[s][ks] = *(const bf8v*)&lb[(s * 64 + wn * 16 + l15) * 64 +
                                           (((ks * 4 + lq) ^ (l15 & 7)) * 8)];
      }
      bf8v aq[2][2];
#pragma unroll
      for (int mi = 0; mi < 2; ++mi)
#pragma unroll
        for (int ks = 0; ks < 2; ++ks)
          aq[mi][ks] = *(const bf8v*)&la[(wm * 128 + (2 * q + mi) * 16 + l15) * 64 +
                                         (((ks * 4 + lq) ^ (l15 & 7)) * 8)];
      if (pf) {
        if (q == 0) { stB(kt + 1, 0); stB(kt + 1, 1); }
        if (q == 1) { stB(kt + 1, 2); stB(kt + 1, 3); }
        if (q == 2) { stA(kt + 1, 0); stA(kt + 1, 2); }  // rounds needed at next P0/P1
        if (q == 3) { stA(kt + 1, 1); stA(kt + 1, 3); }  // rounds needed at next P2/P3
      }
      __builtin_amdgcn_s_barrier();
      asm volatile("s_waitcnt lgkmcnt(0)" ::: "memory");
      __builtin_amdgcn_s_setprio(1);
#pragma unroll
      for (int mi = 0; mi < 2; ++mi)
#pragma unroll
        for (int s = 0; s < NS; ++s)
#pragma unroll
          for (int ks = 0; ks < 2; ++ks)
            acc[2 * q + mi][s] = __builtin_amdgcn_mfma_f32_16x16x32_bf16(
                aq[mi][ks], bfr[s][ks], acc[2 * q + mi][s], 0, 0, 0);
      __builtin_amdgcn_s_setprio(0);
      if (q == 1) {
        // need A rounds 1,3 of THIS tile (issued at prev tile P3) before next reads
        if (pf) asm volatile("s_waitcnt vmcnt(4)" ::: "memory");
        else    asm volatile("s_waitcnt vmcnt(0)" ::: "memory");
      }
      if (q == 3) {
        // need B(all)+A rounds 0,2 of NEXT tile; leave A rounds 1,3 in flight
        asm volatile("s_waitcnt vmcnt(2)" ::: "memory");
      }
      __builtin_amdgcn_s_barrier();
    }
  };
  for (int kt = 0; kt < NKT - 1; ++kt) tile(kt, true);
  tile(NKT - 1, false);
}

__global__ __launch_bounds__(512, 2) void step8_kernel(
    const u16* __restrict__ hbf_in, const float* __restrict__ hf_in,
    float* __restrict__ hf_out, u16* __restrict__ hbf_out,
    const u16* __restrict__ Wb, const u16* __restrict__ gzc,
    const float* __restrict__ d1,
    const float* __restrict__ bhh0v, const float* __restrict__ bhh1v,
    const float* __restrict__ bo0v, const float* __restrict__ bo1v,
    float* __restrict__ dout, int step1, int o_slot, int y_base) {
  __shared__ u16 lds[4 * 16384];  // 128 KiB
  const int dec = blockIdx.z;
  const int ntile = blockIdx.y + y_base;
  const int m0 = blockIdx.x * 256;
  const int lane = threadIdx.x & 63, wid = threadIdx.x >> 6;
  const int wm = wid >> 2, wn = wid & 3;
  const int l15 = lane & 15, lq = lane >> 4;
  const u16* A = hbf_in + (size_t)dec * 2 * BB * HH;
  const u16* W = Wb + (size_t)dec * WR * HH;

  f4v acc[8][4];
#pragma unroll
  for (int mf = 0; mf < 8; ++mf)
#pragma unroll
    for (int s = 0; s < 4; ++s)
#pragma unroll
      for (int r = 0; r < 4; ++r) acc[mf][s][r] = 0.f;

  if (ntile < 16) {
    const int j0 = ntile * 64;
    int brow[4] = {j0, HH + j0, 2 * HH + j0, 3 * HH + j0};
    kloop8<4>(A, W, brow, m0, lds, lane, wid, acc);

    const u16* gz = gzc + (size_t)dec * BB * GG;
    const float* dd = d1 + dec * GG;
    const float* bhhn = (dec ? bhh1v : bhh0v) + 2 * HH;
    const float* hold = hf_in + (size_t)dec * 2 * BB * HH;
    float* hnew = hf_out + (size_t)dec * 2 * BB * HH;
    u16* hnb = hbf_out + (size_t)dec * 2 * BB * HH;
    const int col = j0 + wn * 16 + l15;
    const float bn = bhhn[col];
    const float dr0 = step1 ? dd[col] : 0.f;
    const float dr1 = step1 ? dd[HH + col] : 0.f;
    const float dr2 = step1 ? dd[2 * HH + col] : 0.f;
#pragma unroll
    for (int mf = 0; mf < 8; ++mf) {
#pragma unroll
      for (int r = 0; r < 4; ++r) {
        const int row = m0 + wm * 128 + mf * 16 + lq * 4 + r;
        const size_t ro = (size_t)row * GG;
        float v0 = acc[mf][0][r] + bf2f(gz[ro + col]) + dr0;
        float v1 = acc[mf][1][r] + bf2f(gz[ro + HH + col]) + dr1;
        float v2 = acc[mf][2][r] + bf2f(gz[ro + 2 * HH + col]) + dr2;
        float v3 = acc[mf][3][r] + bn;
        float rg = sigf(v0), zg = sigf(v1);
        float nn = tanh_fast(v2 + rg * v3);
        float hv = hold[(size_t)row * HH + col];
        float hn = (1.f - zg) * nn + zg * hv;
        hnew[(size_t)row * HH + col] = hn;
        hnb[(size_t)row * HH + col] = f2bf(hn);
      }
    }
  } else {
    int brow[4] = {4 * HH, 4 * HH + 64, 4 * HH, 4 * HH + 64};  // rounds 2,3 duplicate
    kloop8<2>(A, W, brow, m0, lds, lane, wid, acc);
    const float* bod = dec ? bo1v : bo0v;
    float* op = dout + (size_t)dec * BB * TT * OO + (size_t)o_slot * OO;
#pragma unroll
    for (int mf = 0; mf < 8; ++mf)
#pragma unroll
      for (int s2 = 0; s2 < 2; ++s2) {
        const int col = s2 * 64 + wn * 16 + l15;
        const float b = bod[col];
#pragma unroll
        for (int r = 0; r < 4; ++r) {
          const int row = m0 + wm * 128 + mf * 16 + lq * 4 + r;
          op[(size_t)row * TT * OO + col] = acc[mf][s2][r] + b;
        }
      }
  }
}

// ---------------- host ----------------

extern "C" void kernel_launch(void* const* d_in, const int* in_sizes, int n_in,
                              void* d_out, int out_size, void* d_ws, size_t ws_size,
                              hipStream_t stream) {
  const float* z8[2] = {(const float*)d_in[0], (const float*)d_in[1]};
  const float* Wi[2] = {(const float*)d_in[4], (const float*)d_in[6]};
  const float* bi[2] = {(const float*)d_in[5], (const float*)d_in[7]};
  const float* Wih[2] = {(const float*)d_in[8], (const float*)d_in[12]};
  const float* Whh[2] = {(const float*)d_in[9], (const float*)d_in[13]};
  const float* bih[2] = {(const float*)d_in[10], (const float*)d_in[14]};
  const float* bhh[2] = {(const float*)d_in[11], (const float*)d_in[15]};
  const float* Wo[2] = {(const float*)d_in[16], (const float*)d_in[18]};
  const float* bo[2] = {(const float*)d_in[17], (const float*)d_in[19]};
  float* dout = (float*)d_out;

  char* p = (char*)d_ws;
  size_t off = 0;
  auto carve = [&](size_t nbytes) {
    char* r = p + off;
    off += (nbytes + 255) & ~(size_t)255;
    return (void*)r;
  };
  float* hf = (float*)carve((size_t)DECN * 2 * BB * HH * 4);
  u16* hbf = (u16*)carve((size_t)DECN * 2 * BB * HH * 2);
  u16* gzc = (u16*)carve((size_t)DECN * BB * GG * 2);
  u16* wb1 = (u16*)carve((size_t)DECN * WR * HH * 2);
  u16* wb2 = (u16*)carve((size_t)DECN * WR * HH * 2);
  u16* zbf = (u16*)carve((size_t)DECN * BB * ZZ * 2);
  u16* wzb = (u16*)carve((size_t)DECN * GG * ZZ * 2);
  u16* wio = (u16*)carve((size_t)DECN * GG * OO * 2);
  u16* wib = (u16*)carve((size_t)DECN * HH * ZZ * 2);
  u16* wot = (u16*)carve((size_t)DECN * HH * OO * 2);
  float* d1v = (float*)carve((size_t)DECN * GG * 4);
  float* v2v = (float*)carve((size_t)DECN * GG * 4);
  (void)ws_size; (void)in_sizes; (void)n_in; (void)out_size;

  auto pack = [&](const float* src, int ld, int c0, u16* dst, int rows, int cols) {
    int n = rows * cols;
    pack_kernel<<<(n + 255) / 256, 256, 0, stream>>>(src, ld, c0, dst, rows, cols);
  };
  for (int d = 0; d < 2; ++d) {
    pack(z8[d], ZZ, 0, zbf + (size_t)d * BB * ZZ, BB, ZZ);
    pack(Wih[d], ILD, OO, wzb + (size_t)d * GG * ZZ, GG, ZZ);
    pack(Wih[d], ILD, 0, wio + (size_t)d * GG * OO, GG, OO);
    pack(Wi[d], ZZ, 0, wib + (size_t)d * HH * ZZ, HH, ZZ);
    pack(Whh[d], HH, 0, wb1 + (size_t)d * WR * HH, 2 * HH, HH);
    pack(Whh[d] + (size_t)2 * HH * HH, HH, 0, wb1 + (size_t)d * WR * HH + (size_t)3 * HH * HH, HH, HH);
    pack(Whh[d] + (size_t)2 * HH * HH, HH, 0, wb2 + (size_t)d * WR * HH + (size_t)3 * HH * HH, HH, HH);
    pack(Wo[d], HH, 0, wb2 + (size_t)d * WR * HH + (size_t)4 * HH * HH, OO, HH);
    wot_kernel<<<(HH * OO + 255) / 256, 256, 0, stream>>>(Wo[d], wot + (size_t)d * HH * OO);
    hipMemsetAsync(wb1 + (size_t)d * WR * HH + (size_t)2 * HH * HH, 0, (size_t)HH * HH * 2, stream);
  }
  vec_kernel<<<(DECN * GG + 255) / 256, 256, 0, stream>>>(
      Wih[0], Wih[1], bih[0], bih[1], bhh[0], bhh[1], bo[0], bo[1], d1v, v2v);
  comb_kernel<<<dim3(24, 16, 2), 256, 0, stream>>>(wio, wot, Whh[0], Whh[1], wb2);
  gzc_kernel<<<dim3(32, 48, 2), 256, 0, stream>>>(zbf, wzb, v2v, gzc);
  h0_kernel<<<dim3(32, 16, 2), 256, 0, stream>>>(zbf, wib, bi[0], bi[1], hf, hbf);

  for (int t = 1; t <= TT; ++t) {
    const int bin = (t - 1) & 1, bout = t & 1;
    dim3 grid(16, t == 1 ? 16 : 17, 2);
    step8_kernel<<<grid, 512, 0, stream>>>(
        hbf + (size_t)bin * BB * HH, hf + (size_t)bin * BB * HH,
        hf + (size_t)bout * BB * HH, hbf + (size_t)bout * BB * HH,
        t == 1 ? wb1 : wb2, gzc, d1v, bhh[0], bhh[1], bo[0], bo[1],
        dout, t == 1 ? 1 : 0, t - 2, 0);
  }
  // final o_32 (h_32 lives in buf 0)
  step8_kernel<<<dim3(16, 1, 2), 512, 0, stream>>>(
      hbf, hf, hf + (size_t)BB * HH, hbf + (size_t)BB * HH,
      wb2, gzc, d1v, bhh[0], bhh[1], bo[0], bo[1],
      dout, 0, TT - 1, 16);
}

// Round 6
// 3131.073 us; speedup vs baseline: 1.0945x; 1.0249x over previous
//
#include <hip/hip_runtime.h>
#include <stdint.h>

// Round 6: exact-grid step kernel (512 blocks = 2 rounds), o-projection extracted
// to one final GEMM over all stored h_t (ws_size-gated with R5 fallback), and
// fragment-aligned transposed layouts (gzt, hft col-major) for vectorized epilogue.

typedef unsigned short u16;
typedef __attribute__((ext_vector_type(8))) short bf8v;
typedef __attribute__((ext_vector_type(4))) float f4v;
typedef __attribute__((ext_vector_type(4))) unsigned short us4v;

constexpr int DECN = 2;
constexpr int BB = 4096;
constexpr int HH = 1024;
constexpr int ZZ = 256;
constexpr int OO = 128;
constexpr int TT = 32;
constexpr int GG = 3 * HH;
constexpr int WR = 4 * HH + OO;
constexpr int ILD = OO + ZZ;
constexpr int BK = 64;
constexpr int NKT = HH / BK;

__device__ __forceinline__ float bf2f(u16 u) {
  uint32_t x = ((uint32_t)u) << 16;
  return __builtin_bit_cast(float, x);
}
__device__ __forceinline__ u16 f2bf(float f) {
  uint32_t x = __builtin_bit_cast(uint32_t, f);
  x += 0x7fffu + ((x >> 16) & 1u);
  return (u16)(x >> 16);
}
__device__ __forceinline__ float sigf(float x) { return 1.f / (1.f + __expf(-x)); }
__device__ __forceinline__ float tanh_fast(float x) { return 2.f / (1.f + __expf(-2.f * x)) - 1.f; }

__device__ __forceinline__ void load16(const u16* g, u16* l) {
  __builtin_amdgcn_global_load_lds(
      (const __attribute__((address_space(1))) unsigned int*)g,
      (__attribute__((address_space(3))) unsigned int*)l, 16, 0, 0);
}

// ---------------- round-1 gemm core (prep kernels only) ----------------
template <int NSEC>
__device__ __forceinline__ void gemm_core(
    const u16* __restrict__ A, int lda,
    const u16* __restrict__ Bm, int ldb,
    const int (&brow)[NSEC], int m0, int K,
    u16* Als, u16* Bls, f4v (&acc)[NSEC][4][2]) {
  const int tid = threadIdx.x;
  const int lane = tid & 63;
  const int wid = tid >> 6;
  const int wm = wid >> 1, wn = wid & 1;
  const int srow = lane >> 2;
  const int scol = (lane & 3) * 8;
  const int l15 = lane & 15;
  const int khalf = (lane >> 4) * 8;

  for (int k0 = 0; k0 < K; k0 += 32) {
    const u16* ga = A + (size_t)(m0 + wid * 16 + srow) * lda + k0 + scol;
    load16(ga, Als + (wid * 16) * 32);
    load16(ga + (size_t)64 * lda, Als + (64 + wid * 16) * 32);
#pragma unroll
    for (int s = 0; s < NSEC; ++s) {
      const u16* gb = Bm + (size_t)(brow[s] + wid * 16 + srow) * ldb + k0 + scol;
      load16(gb, Bls + (s * 64 + wid * 16) * 32);
    }
    __syncthreads();
    bf8v af[4];
#pragma unroll
    for (int mf = 0; mf < 4; ++mf)
      af[mf] = *(const bf8v*)(Als + (wm * 64 + mf * 16 + l15) * 32 + khalf);
#pragma unroll
    for (int s = 0; s < NSEC; ++s) {
#pragma unroll
      for (int nf = 0; nf < 2; ++nf) {
        bf8v bv = *(const bf8v*)(Bls + (s * 64 + wn * 32 + nf * 16 + l15) * 32 + khalf);
#pragma unroll
        for (int mf = 0; mf < 4; ++mf)
          acc[s][mf][nf] = __builtin_amdgcn_mfma_f32_16x16x32_bf16(af[mf], bv, acc[s][mf][nf], 0, 0, 0);
      }
    }
    __syncthreads();
  }
}

// ---------------- prep kernels ----------------

__global__ __launch_bounds__(256) void pack_kernel(const float* __restrict__ src, int ld, int col0,
                                                   u16* __restrict__ dst, int rows, int cols) {
  int i = blockIdx.x * 256 + threadIdx.x;
  if (i < rows * cols) {
    int r = i / cols, c = i - r * cols;
    dst[i] = f2bf(src[(size_t)r * ld + col0 + c]);
  }
}

__global__ __launch_bounds__(256) void wot_kernel(const float* __restrict__ wo, u16* __restrict__ dst) {
  int i = blockIdx.x * 256 + threadIdx.x;
  if (i < HH * OO) {
    int k = i / OO, c = i - k * OO;
    dst[i] = f2bf(wo[(size_t)c * HH + k]);
  }
}

__global__ __launch_bounds__(256) void vec_kernel(
    const float* __restrict__ wih0, const float* __restrict__ wih1,
    const float* __restrict__ bih0, const float* __restrict__ bih1,
    const float* __restrict__ bhh0, const float* __restrict__ bhh1,
    const float* __restrict__ bo0, const float* __restrict__ bo1,
    float* __restrict__ d1, float* __restrict__ v2) {
  int i = blockIdx.x * 256 + threadIdx.x;
  if (i >= DECN * GG) return;
  int dec = i / GG, j = i - dec * GG;
  const float* wih = dec ? wih1 : wih0;
  const float* bo = dec ? bo1 : bo0;
  const float* bih = dec ? bih1 : bih0;
  const float* bhh = dec ? bhh1 : bhh0;
  float bc = 0.f;
  for (int c = 0; c < OO; ++c) bc += wih[(size_t)j * ILD + c] * bo[c];
  d1[i] = wih[(size_t)j * ILD + (OO - 1)] - bc;
  v2[i] = bih[j] + (j < 2 * HH ? bhh[j] : 0.f) + bc;
}

__global__ __launch_bounds__(256, 2) void comb_kernel(
    const u16* __restrict__ wio, const u16* __restrict__ wot,
    const float* __restrict__ whh0, const float* __restrict__ whh1,
    u16* __restrict__ wb2) {
  __shared__ u16 Als[128 * 32];
  __shared__ u16 Bls[64 * 32];
  const int dec = blockIdx.z, m0 = blockIdx.x * 128, n0 = blockIdx.y * 64;
  const int lane = threadIdx.x & 63, wid = threadIdx.x >> 6;
  const int wm = wid >> 1, wn = wid & 1;
  const int rbase = m0 + wm * 64 + ((lane >> 4) << 2);
  const int clb = wn * 32 + (lane & 15);
  int brow[1] = {n0};
  f4v acc[1][4][2];
#pragma unroll
  for (int mf = 0; mf < 4; ++mf)
#pragma unroll
    for (int nf = 0; nf < 2; ++nf)
#pragma unroll
      for (int r = 0; r < 4; ++r) acc[0][mf][nf][r] = 0.f;
  gemm_core<1>(wio + (size_t)dec * GG * OO, OO, wot + (size_t)dec * HH * OO, OO, brow, m0, OO, Als, Bls, acc);
  const float* whh = dec ? whh1 : whh0;
  u16* W2 = wb2 + (size_t)dec * WR * HH;
#pragma unroll
  for (int mf = 0; mf < 4; ++mf)
#pragma unroll
    for (int nf = 0; nf < 2; ++nf) {
      const int k = n0 + clb + nf * 16;
#pragma unroll
      for (int r = 0; r < 4; ++r) {
        const int j = rbase + mf * 16 + r;
        float v = acc[0][mf][nf][r] + (j < 2 * HH ? whh[(size_t)j * HH + k] : 0.f);
        W2[(size_t)j * HH + k] = f2bf(v);
      }
    }
}

// gzt = transposed z-contribution: [dec][gate 0..2][col 0..1023][row 0..4095] bf16
__global__ __launch_bounds__(256, 2) void gzc_kernel(
    const u16* __restrict__ zbf, const u16* __restrict__ wzb,
    const float* __restrict__ v2, u16* __restrict__ gzt) {
  __shared__ u16 Als[128 * 32];
  __shared__ u16 Bls[64 * 32];
  const int dec = blockIdx.z, m0 = blockIdx.x * 128, n0 = blockIdx.y * 64;
  const int lane = threadIdx.x & 63, wid = threadIdx.x >> 6;
  const int wm = wid >> 1, wn = wid & 1;
  const int rbase = m0 + wm * 64 + ((lane >> 4) << 2);
  const int clb = wn * 32 + (lane & 15);
  int brow[1] = {n0};
  f4v acc[1][4][2];
#pragma unroll
  for (int mf = 0; mf < 4; ++mf)
#pragma unroll
    for (int nf = 0; nf < 2; ++nf)
#pragma unroll
      for (int r = 0; r < 4; ++r) acc[0][mf][nf][r] = 0.f;
  gemm_core<1>(zbf + (size_t)dec * BB * ZZ, ZZ, wzb + (size_t)dec * GG * ZZ, ZZ, brow, m0, ZZ, Als, Bls, acc);
  const float* vv = v2 + dec * GG;
  u16* out = gzt + (size_t)dec * 3 * HH * BB;
#pragma unroll
  for (int mf = 0; mf < 4; ++mf)
#pragma unroll
    for (int nf = 0; nf < 2; ++nf) {
      const int colg = n0 + clb + nf * 16;
      const int g = colg >> 10, cc = colg & 1023;
      us4v v;
#pragma unroll
      for (int r = 0; r < 4; ++r) v[r] = f2bf(acc[0][mf][nf][r] + vv[colg]);
      *(us4v*)(out + ((size_t)g * HH + cc) * BB + rbase + mf * 16) = v;
    }
}

// h0: f32 col-major into hft slot 0, bf16 row-major into hst slot 0
__global__ __launch_bounds__(256, 2) void h0_kernel(
    const u16* __restrict__ zbf, const u16* __restrict__ wib,
    const float* __restrict__ bi0, const float* __restrict__ bi1,
    float* __restrict__ hft, u16* __restrict__ hst, int slots) {
  __shared__ u16 Als[128 * 32];
  __shared__ u16 Bls[64 * 32];
  const int dec = blockIdx.z, m0 = blockIdx.x * 128, n0 = blockIdx.y * 64;
  const int lane = threadIdx.x & 63, wid = threadIdx.x >> 6;
  const int wm = wid >> 1, wn = wid & 1;
  const int rbase = m0 + wm * 64 + ((lane >> 4) << 2);
  const int clb = wn * 32 + (lane & 15);
  int brow[1] = {n0};
  f4v acc[1][4][2];
#pragma unroll
  for (int mf = 0; mf < 4; ++mf)
#pragma unroll
    for (int nf = 0; nf < 2; ++nf)
#pragma unroll
      for (int r = 0; r < 4; ++r) acc[0][mf][nf][r] = 0.f;
  gemm_core<1>(zbf + (size_t)dec * BB * ZZ, ZZ, wib + (size_t)dec * HH * ZZ, ZZ, brow, m0, ZZ, Als, Bls, acc);
  const float* bi = dec ? bi1 : bi0;
  float* ho = hft + (size_t)dec * 2 * HH * BB;               // slot 0
  u16* hb = hst + (size_t)dec * slots * BB * HH;             // slot 0
#pragma unroll
  for (int mf = 0; mf < 4; ++mf)
#pragma unroll
    for (int nf = 0; nf < 2; ++nf) {
      const int col = n0 + clb + nf * 16;
      f4v hv;
#pragma unroll
      for (int r = 0; r < 4; ++r) {
        const int row = rbase + mf * 16 + r;
        float v = tanh_fast(acc[0][mf][nf][r] + bi[col]);
        hv[r] = v;
        hb[(size_t)row * HH + col] = f2bf(v);
      }
      *(f4v*)(ho + (size_t)col * BB + rbase + mf * 16) = hv;
    }
}

// ---------------- 8-phase K-loop (unchanged from R5) ----------------
template <int NS>
__device__ __forceinline__ void kloop8(
    const u16* __restrict__ A, const u16* __restrict__ W,
    const int (&brow)[4], int m0, u16* lds, int lane, int wid,
    f4v (&acc)[8][4]) {
  const int wm = wid >> 2, wn = wid & 3;
  const int l15 = lane & 15, lq = lane >> 4;
  const int srow = wid * 8 + (lane >> 3);
  const int sgc = (lane & 7) ^ ((lane >> 3) & 7);

  auto stA = [&](int kt, int r) {
    const u16* g = A + (size_t)(m0 + r * 64 + srow) * HH + kt * BK + sgc * 8;
    load16(g, lds + ((kt & 1) * 2) * 16384 + (r * 64 + wid * 8) * 64);
  };
  auto stB = [&](int kt, int r) {
    const u16* g = W + (size_t)(brow[r] + srow) * HH + kt * BK + sgc * 8;
    load16(g, lds + ((kt & 1) * 2 + 1) * 16384 + (r * 64 + wid * 8) * 64);
  };

  stB(0, 0); stB(0, 1); stB(0, 2); stB(0, 3);
  stA(0, 0); stA(0, 1); stA(0, 2); stA(0, 3);
  asm volatile("s_waitcnt vmcnt(0)" ::: "memory");
  __builtin_amdgcn_s_barrier();

  auto tile = [&](int kt, bool pf) {
    const u16* la = lds + (size_t)(kt & 1) * 32768;
    const u16* lb = la + 16384;
    bf8v bfr[NS][2];
#pragma unroll
    for (int q = 0; q < 4; ++q) {
      if (q == 0) {
#pragma unroll
        for (int s = 0; s < NS; ++s)
#pragma unroll
          for (int ks = 0; ks < 2; ++ks)
            bfr[s][ks] = *(const bf8v*)&lb[(s * 64 + wn * 16 + l15) * 64 +
                                           (((ks * 4 + lq) ^ (l15 & 7)) * 8)];
      }
      bf8v aq[2][2];
#pragma unroll
      for (int mi = 0; mi < 2; ++mi)
#pragma unroll
        for (int ks = 0; ks < 2; ++ks)
          aq[mi][ks] = *(const bf8v*)&la[(wm * 128 + (2 * q + mi) * 16 + l15) * 64 +
                                         (((ks * 4 + lq) ^ (l15 & 7)) * 8)];
      if (pf) {
        if (q == 0) { stB(kt + 1, 0); stB(kt + 1, 1); }
        if (q == 1) { stB(kt + 1, 2); stB(kt + 1, 3); }
        if (q == 2) { stA(kt + 1, 0); stA(kt + 1, 2); }
        if (q == 3) { stA(kt + 1, 1); stA(kt + 1, 3); }
      }
      __builtin_amdgcn_s_barrier();
      asm volatile("s_waitcnt lgkmcnt(0)" ::: "memory");
      __builtin_amdgcn_s_setprio(1);
#pragma unroll
      for (int mi = 0; mi < 2; ++mi)
#pragma unroll
        for (int s = 0; s < NS; ++s)
#pragma unroll
          for (int ks = 0; ks < 2; ++ks)
            acc[2 * q + mi][s] = __builtin_amdgcn_mfma_f32_16x16x32_bf16(
                aq[mi][ks], bfr[s][ks], acc[2 * q + mi][s], 0, 0, 0);
      __builtin_amdgcn_s_setprio(0);
      if (q == 1) {
        if (pf) asm volatile("s_waitcnt vmcnt(4)" ::: "memory");
        else    asm volatile("s_waitcnt vmcnt(0)" ::: "memory");
      }
      if (q == 3) {
        asm volatile("s_waitcnt vmcnt(2)" ::: "memory");
      }
      __builtin_amdgcn_s_barrier();
    }
  };
  for (int kt = 0; kt < NKT - 1; ++kt) tile(kt, true);
  tile(NKT - 1, false);
}

// ---------------- step kernel ----------------
__global__ __launch_bounds__(512, 2) void step8_kernel(
    const u16* __restrict__ hst, float* __restrict__ hft,
    const u16* __restrict__ Wb, const u16* __restrict__ gzt,
    const float* __restrict__ d1,
    const float* __restrict__ bhh0v, const float* __restrict__ bhh1v,
    const float* __restrict__ bo0v, const float* __restrict__ bo1v,
    float* __restrict__ dout, int step1, int o_slot, int y_base,
    int slots, int slot_in, int slot_out, int sin, int sout) {
  __shared__ u16 lds[4 * 16384];
  const int dec = blockIdx.z;
  const int ntile = blockIdx.y + y_base;
  const int m0 = blockIdx.x * 256;
  const int lane = threadIdx.x & 63, wid = threadIdx.x >> 6;
  const int wm = wid >> 2, wn = wid & 3;
  const int l15 = lane & 15, lq = lane >> 4;
  const size_t SZ = (size_t)BB * HH;
  const u16* A = hst + ((size_t)dec * slots + slot_in) * SZ;
  const u16* W = Wb + (size_t)dec * WR * HH;

  f4v acc[8][4];
#pragma unroll
  for (int mf = 0; mf < 8; ++mf)
#pragma unroll
    for (int s = 0; s < 4; ++s)
#pragma unroll
      for (int r = 0; r < 4; ++r) acc[mf][s][r] = 0.f;

  if (ntile < 16) {
    const int j0 = ntile * 64;
    int brow[4] = {j0, HH + j0, 2 * HH + j0, 3 * HH + j0};
    kloop8<4>(A, W, brow, m0, lds, lane, wid, acc);

    const int col = j0 + wn * 16 + l15;
    const float* dd = d1 + dec * GG;
    const float bn = ((dec ? bhh1v : bhh0v) + 2 * HH)[col];
    const float dr0 = step1 ? dd[col] : 0.f;
    const float dr1 = step1 ? dd[HH + col] : 0.f;
    const float dr2 = step1 ? dd[2 * HH + col] : 0.f;
    const u16* gzb = gzt + (size_t)dec * 3 * HH * BB;
    const u16* g0p = gzb + (size_t)col * BB;
    const u16* g1p = gzb + ((size_t)HH + col) * BB;
    const u16* g2p = gzb + ((size_t)2 * HH + col) * BB;
    const float* hvp = hft + ((size_t)dec * 2 + sin) * ((size_t)HH * BB) + (size_t)col * BB;
    float* hop = hft + ((size_t)dec * 2 + sout) * ((size_t)HH * BB) + (size_t)col * BB;
    u16* hnbp = (u16*)hst + ((size_t)dec * slots + slot_out) * SZ;  // row-major bf16
#pragma unroll
    for (int mf = 0; mf < 8; ++mf) {
      const int row0 = m0 + wm * 128 + mf * 16 + lq * 4;
      us4v g0 = *(const us4v*)(g0p + row0);
      us4v g1 = *(const us4v*)(g1p + row0);
      us4v g2 = *(const us4v*)(g2p + row0);
      f4v hv4 = *(const f4v*)(hvp + row0);
      f4v hn4;
#pragma unroll
      for (int r = 0; r < 4; ++r) {
        float v0 = acc[mf][0][r] + bf2f(g0[r]) + dr0;
        float v1 = acc[mf][1][r] + bf2f(g1[r]) + dr1;
        float v2 = acc[mf][2][r] + bf2f(g2[r]) + dr2;
        float v3 = acc[mf][3][r] + bn;
        float rg = sigf(v0), zg = sigf(v1);
        float nn = tanh_fast(v2 + rg * v3);
        float hn = (1.f - zg) * nn + zg * hv4[r];
        hn4[r] = hn;
        hnbp[(size_t)(row0 + r) * HH + col] = f2bf(hn);
      }
      *(f4v*)(hop + row0) = hn4;
    }
  } else {
    // fallback-mode o-projection tile (unchanged from R5)
    int brow[4] = {4 * HH, 4 * HH + 64, 4 * HH, 4 * HH + 64};
    kloop8<2>(A, W, brow, m0, lds, lane, wid, acc);
    const float* bod = dec ? bo1v : bo0v;
    float* op = dout + (size_t)dec * BB * TT * OO + (size_t)o_slot * OO;
#pragma unroll
    for (int mf = 0; mf < 8; ++mf)
#pragma unroll
      for (int s2 = 0; s2 < 2; ++s2) {
        const int col = s2 * 64 + wn * 16 + l15;
        const float b = bod[col];
#pragma unroll
        for (int r = 0; r < 4; ++r) {
          const int row = m0 + wm * 128 + mf * 16 + lq * 4 + r;
          op[(size_t)row * TT * OO + col] = acc[mf][s2][r] + b;
        }
      }
  }
}

// All-step o-projection: O[dec][t][b] = h_t @ Wo^T + bo, M = 32*4096 rows per dec.
__global__ __launch_bounds__(512, 2) void ogemm_kernel(
    const u16* __restrict__ hst, const u16* __restrict__ Wb,
    const float* __restrict__ bo0v, const float* __restrict__ bo1v,
    float* __restrict__ dout) {
  __shared__ u16 lds[4 * 16384];
  const int dec = blockIdx.z;
  const int m0 = blockIdx.x * 256;
  const int lane = threadIdx.x & 63, wid = threadIdx.x >> 6;
  const int wm = wid >> 2, wn = wid & 3;
  const int l15 = lane & 15, lq = lane >> 4;
  const size_t SZ = (size_t)BB * HH;
  const u16* A = hst + (size_t)dec * 33 * SZ + SZ;  // slots 1..32
  const u16* W = Wb + (size_t)dec * WR * HH;

  f4v acc[8][4];
#pragma unroll
  for (int mf = 0; mf < 8; ++mf)
#pragma unroll
    for (int s = 0; s < 4; ++s)
#pragma unroll
      for (int r = 0; r < 4; ++r) acc[mf][s][r] = 0.f;

  int brow[4] = {4 * HH, 4 * HH + 64, 4 * HH, 4 * HH + 64};
  kloop8<2>(A, W, brow, m0, lds, lane, wid, acc);
  const float* bod = dec ? bo1v : bo0v;
  float* op = dout + (size_t)dec * BB * TT * OO;
#pragma unroll
  for (int mf = 0; mf < 8; ++mf)
#pragma unroll
    for (int s2 = 0; s2 < 2; ++s2) {
      const int col = s2 * 64 + wn * 16 + l15;
      const float b = bod[col];
#pragma unroll
      for (int r = 0; r < 4; ++r) {
        const int mrow = m0 + wm * 128 + mf * 16 + lq * 4 + r;
        const int t = mrow >> 12, bb = mrow & (BB - 1);
        op[(size_t)bb * TT * OO + t * OO + col] = acc[mf][s2][r] + b;
      }
    }
}

// ---------------- host ----------------

extern "C" void kernel_launch(void* const* d_in, const int* in_sizes, int n_in,
                              void* d_out, int out_size, void* d_ws, size_t ws_size,
                              hipStream_t stream) {
  const float* z8[2] = {(const float*)d_in[0], (const float*)d_in[1]};
  const float* Wi[2] = {(const float*)d_in[4], (const float*)d_in[6]};
  const float* bi[2] = {(const float*)d_in[5], (const float*)d_in[7]};
  const float* Wih[2] = {(const float*)d_in[8], (const float*)d_in[12]};
  const float* Whh[2] = {(const float*)d_in[9], (const float*)d_in[13]};
  const float* bih[2] = {(const float*)d_in[10], (const float*)d_in[14]};
  const float* bhh[2] = {(const float*)d_in[11], (const float*)d_in[15]};
  const float* Wo[2] = {(const float*)d_in[16], (const float*)d_in[18]};
  const float* bo[2] = {(const float*)d_in[17], (const float*)d_in[19]};
  float* dout = (float*)d_out;

  const size_t SZ = (size_t)BB * HH;
  const bool big = ws_size >= (size_t)760 * 1024 * 1024;
  const int slots = big ? 33 : 2;

  char* p = (char*)d_ws;
  size_t off = 0;
  auto carve = [&](size_t nbytes) {
    char* r = p + off;
    off += (nbytes + 255) & ~(size_t)255;
    return (void*)r;
  };
  float* hft = (float*)carve((size_t)DECN * 2 * SZ * 4);        // [dec][2][col][row] f32
  u16* hst = (u16*)carve((size_t)DECN * slots * SZ * 2);        // [dec][slot][row][col] bf16
  u16* gzt = (u16*)carve((size_t)DECN * 3 * HH * BB * 2);       // [dec][gate][col][row]
  u16* wb1 = (u16*)carve((size_t)DECN * WR * HH * 2);
  u16* wb2 = (u16*)carve((size_t)DECN * WR * HH * 2);
  u16* zbf = (u16*)carve((size_t)DECN * BB * ZZ * 2);
  u16* wzb = (u16*)carve((size_t)DECN * GG * ZZ * 2);
  u16* wio = (u16*)carve((size_t)DECN * GG * OO * 2);
  u16* wib = (u16*)carve((size_t)DECN * HH * ZZ * 2);
  u16* wot = (u16*)carve((size_t)DECN * HH * OO * 2);
  float* d1v = (float*)carve((size_t)DECN * GG * 4);
  float* v2v = (float*)carve((size_t)DECN * GG * 4);
  (void)in_sizes; (void)n_in; (void)out_size;

  auto pack = [&](const float* src, int ld, int c0, u16* dst, int rows, int cols) {
    int n = rows * cols;
    pack_kernel<<<(n + 255) / 256, 256, 0, stream>>>(src, ld, c0, dst, rows, cols);
  };
  for (int d = 0; d < 2; ++d) {
    pack(z8[d], ZZ, 0, zbf + (size_t)d * BB * ZZ, BB, ZZ);
    pack(Wih[d], ILD, OO, wzb + (size_t)d * GG * ZZ, GG, ZZ);
    pack(Wih[d], ILD, 0, wio + (size_t)d * GG * OO, GG, OO);
    pack(Wi[d], ZZ, 0, wib + (size_t)d * HH * ZZ, HH, ZZ);
    pack(Whh[d], HH, 0, wb1 + (size_t)d * WR * HH, 2 * HH, HH);
    pack(Whh[d] + (size_t)2 * HH * HH, HH, 0, wb1 + (size_t)d * WR * HH + (size_t)3 * HH * HH, HH, HH);
    pack(Whh[d] + (size_t)2 * HH * HH, HH, 0, wb2 + (size_t)d * WR * HH + (size_t)3 * HH * HH, HH, HH);
    pack(Wo[d], HH, 0, wb2 + (size_t)d * WR * HH + (size_t)4 * HH * HH, OO, HH);
    wot_kernel<<<(HH * OO + 255) / 256, 256, 0, stream>>>(Wo[d], wot + (size_t)d * HH * OO);
    hipMemsetAsync(wb1 + (size_t)d * WR * HH + (size_t)2 * HH * HH, 0, (size_t)HH * HH * 2, stream);
  }
  vec_kernel<<<(DECN * GG + 255) / 256, 256, 0, stream>>>(
      Wih[0], Wih[1], bih[0], bih[1], bhh[0], bhh[1], bo[0], bo[1], d1v, v2v);
  comb_kernel<<<dim3(24, 16, 2), 256, 0, stream>>>(wio, wot, Whh[0], Whh[1], wb2);
  gzc_kernel<<<dim3(32, 48, 2), 256, 0, stream>>>(zbf, wzb, v2v, gzt);
  h0_kernel<<<dim3(32, 16, 2), 256, 0, stream>>>(zbf, wib, bi[0], bi[1], hft, hst, slots);

  for (int t = 1; t <= TT; ++t) {
    const int slot_in = big ? t - 1 : (t - 1) & 1;
    const int slot_out = big ? t : t & 1;
    const int sin = (t - 1) & 1, sout = t & 1;
    dim3 grid(16, big ? 16 : (t == 1 ? 16 : 17), 2);
    step8_kernel<<<grid, 512, 0, stream>>>(
        hst, hft, t == 1 ? wb1 : wb2, gzt, d1v, bhh[0], bhh[1], bo[0], bo[1],
        dout, t == 1 ? 1 : 0, t - 2, 0, slots, slot_in, slot_out, sin, sout);
  }
  if (big) {
    ogemm_kernel<<<dim3(512, 1, 2), 512, 0, stream>>>(hst, wb2, bo[0], bo[1], dout);
  } else {
    // fallback: final o_32 (h_32 in slot 0)
    step8_kernel<<<dim3(16, 1, 2), 512, 0, stream>>>(
        hst, hft, wb2, gzt, d1v, bhh[0], bhh[1], bo[0], bo[1],
        dout, 0, TT - 1, 16, slots, 0, 1, 0, 1);
  }
}